// Round 2
// baseline (1142.545 us; speedup 1.0000x reference)
//
#include <hip/hip_runtime.h>

#define NTOK 49
#define CDIM 192
#define NHEAD 6
#define HDIM 32

typedef float f32x4 __attribute__((ext_vector_type(4), may_alias));
typedef short b16x8 __attribute__((ext_vector_type(8), may_alias));
typedef short b16x4 __attribute__((ext_vector_type(4), may_alias));

__device__ __forceinline__ f32x4 MFMA(b16x8 a, b16x8 b, f32x4 c) {
  return __builtin_amdgcn_mfma_f32_16x16x32_bf16(a, b, c, 0, 0, 0);
}

__device__ __forceinline__ short f2bf(float f) {
  unsigned u = __builtin_bit_cast(unsigned, f);
  u += 0x7FFFu + ((u >> 16) & 1u);   // round-to-nearest-even
  return (short)(u >> 16);
}

// ---- prep: fp32 weights -> bf16 in workspace ----
// ws (shorts): [0,36864) Wq*scale | [36864,110592) Wkv | [110592,147456) Wo
__global__ void prep_kernel(const float* __restrict__ Wq, const float* __restrict__ Wkv,
                            const float* __restrict__ Wo, short* __restrict__ wsW) {
  const float scale = 0.17677669529663687f;  // D^-0.5
  for (int i = blockIdx.x * 256 + threadIdx.x; i < 147456; i += gridDim.x * 256) {
    float v;
    if (i < 36864)        v = Wq[i] * scale;
    else if (i < 110592)  v = Wkv[i - 36864];
    else                  v = Wo[i - 110592];
    wsW[i] = f2bf(v);
  }
}

// Fused window-MSA: one window per block, 4 waves (256 threads).
// MFMA convention (m89-verified): D[r][c] = sum_k A[r][k]*B[c][k] with
// A-frag lane r=l&15 holding 8 contiguous k at k0=8*(l>>4); same for B-frag
// (col c=l&15); D: col=l&15, row=4*(l>>4)+reg.
__global__ __launch_bounds__(256, 1) void wmsa_kernel(
    const float* __restrict__ qg, const float* __restrict__ kvg,
    const float* __restrict__ maskg, const float* __restrict__ bq,
    const float* __restrict__ bkv, const float* __restrict__ bo,
    const float* __restrict__ rpb, const short* __restrict__ wsW,
    float* __restrict__ outg, int nW) {
  constexpr int SP = 200;  // row stride for [64][192] tiles (2-way bank alias only)
  constexpr int VP = 68;   // vhT row stride (conflict-free)
  constexpr int PP = 72;   // P row stride
  __shared__ short lds[64 * SP * 3 + 192 * VP + 4 * 16 * PP];  // 112128 B
  short* STG = lds;                // staging: kv, then q, then x
  short* QHS = lds + 64 * SP;      // qh * scale
  short* KHS = lds + 2 * 64 * SP;  // kh
  short* VHT = lds + 3 * 64 * SP;  // [192][VP], vhT[c][token]
  short* PBF = VHT + 192 * VP;     // per-wave [16][PP]

  const int b = blockIdx.x;
  const int tid = threadIdx.x;
  const int w = tid >> 6;
  const int lane = tid & 63;
  const int l15 = lane & 15;
  const int lg = lane >> 4;
  const float scale = 0.17677669529663687f;
  const f32x4 zero4 = {0.f, 0.f, 0.f, 0.f};

  const short* WqB = wsW;
  const short* WkvB = wsW + 36864;
  const short* WoB = wsW + 110592;

  const float* qsrc = qg + (size_t)b * (NTOK * CDIM);
  const float* kvsrc = kvg + (size_t)b * (NTOK * CDIM);

  // ---- issue q loads early; consumed after kv-projection (hides HBM latency) ----
  f32x4 qreg[12];
#pragma unroll
  for (int it = 0; it < 12; ++it) {
    int idx = tid + it * 256;
    int r = idx / 48, c4 = idx % 48;
    qreg[it] = (r < NTOK) ? *(const f32x4*)(qsrc + r * CDIM + c4 * 4) : zero4;
  }
  // ---- stage kv -> STG (bf16, rows 49..63 zeroed) ----
#pragma unroll
  for (int it = 0; it < 12; ++it) {
    int idx = tid + it * 256;
    int r = idx / 48, c4 = idx % 48;
    f32x4 v = (r < NTOK) ? *(const f32x4*)(kvsrc + r * CDIM + c4 * 4) : zero4;
    b16x4 o = {f2bf(v[0]), f2bf(v[1]), f2bf(v[2]), f2bf(v[3])};
    *(b16x4*)(STG + r * SP + c4 * 4) = o;
  }
  __syncthreads();

  // ---- kv projection: cols 0..383; wave w -> nt = w*6 + p*3 + {0,1,2} ----
#pragma unroll 1
  for (int p = 0; p < 2; ++p) {
    f32x4 acc[3][4];
#pragma unroll
    for (int j = 0; j < 3; ++j)
#pragma unroll
      for (int m = 0; m < 4; ++m) acc[j][m] = zero4;
    const int nt0 = w * 6 + p * 3;
#pragma unroll
    for (int kk = 0; kk < 6; ++kk) {
      b16x8 a[4];
#pragma unroll
      for (int m = 0; m < 4; ++m)
        a[m] = *(const b16x8*)(STG + (m * 16 + l15) * SP + kk * 32 + lg * 8);
#pragma unroll
      for (int j = 0; j < 3; ++j) {
        const int col = (nt0 + j) * 16 + l15;
        b16x8 bw = *(const b16x8*)(WkvB + col * CDIM + kk * 32 + lg * 8);
#pragma unroll
        for (int m = 0; m < 4; ++m) acc[j][m] = MFMA(a[m], bw, acc[j][m]);
      }
    }
#pragma unroll
    for (int j = 0; j < 3; ++j) {
      const int col = (nt0 + j) * 16 + l15;
      const float bias = bkv[col];
      if (col < CDIM) {  // K half -> KHS[token][col]
#pragma unroll
        for (int m = 0; m < 4; ++m)
#pragma unroll
          for (int r = 0; r < 4; ++r)
            KHS[(m * 16 + lg * 4 + r) * SP + col] = f2bf(acc[j][m][r] + bias);
      } else {  // V half -> transposed VHT[c][token]
        const int c = col - CDIM;
#pragma unroll
        for (int m = 0; m < 4; ++m) {
          b16x4 o = {f2bf(acc[j][m][0] + bias), f2bf(acc[j][m][1] + bias),
                     f2bf(acc[j][m][2] + bias), f2bf(acc[j][m][3] + bias)};
          *(b16x4*)(VHT + c * VP + m * 16 + lg * 4) = o;
        }
      }
    }
  }
  __syncthreads();  // kv consumed; KHS/VHT ready

  // ---- write q (from regs) into STG ----
#pragma unroll
  for (int it = 0; it < 12; ++it) {
    int idx = tid + it * 256;
    int r = idx / 48, c4 = idx % 48;
    b16x4 o = {f2bf(qreg[it][0]), f2bf(qreg[it][1]), f2bf(qreg[it][2]), f2bf(qreg[it][3])};
    *(b16x4*)(STG + r * SP + c4 * 4) = o;
  }
  __syncthreads();

  // ---- q projection (pre-scaled weights): wave w -> nt = w*3 + {0,1,2} ----
  {
    f32x4 acc[3][4];
#pragma unroll
    for (int j = 0; j < 3; ++j)
#pragma unroll
      for (int m = 0; m < 4; ++m) acc[j][m] = zero4;
    const int nt0 = w * 3;
#pragma unroll
    for (int kk = 0; kk < 6; ++kk) {
      b16x8 a[4];
#pragma unroll
      for (int m = 0; m < 4; ++m)
        a[m] = *(const b16x8*)(STG + (m * 16 + l15) * SP + kk * 32 + lg * 8);
#pragma unroll
      for (int j = 0; j < 3; ++j) {
        const int col = (nt0 + j) * 16 + l15;
        b16x8 bw = *(const b16x8*)(WqB + col * CDIM + kk * 32 + lg * 8);
#pragma unroll
        for (int m = 0; m < 4; ++m) acc[j][m] = MFMA(a[m], bw, acc[j][m]);
      }
    }
#pragma unroll
    for (int j = 0; j < 3; ++j) {
      const int col = (nt0 + j) * 16 + l15;
      const float bias = bq[col] * scale;
#pragma unroll
      for (int m = 0; m < 4; ++m)
#pragma unroll
        for (int r = 0; r < 4; ++r)
          QHS[(m * 16 + lg * 4 + r) * SP + col] = f2bf(acc[j][m][r] + bias);
    }
  }
  __syncthreads();

  // ---- attention: wave w owns q-rows w*16..w*16+15; loop heads ----
  const float* maskw = maskg + (size_t)(b % nW) * (NTOK * NTOK);
  short* PB = PBF + w * (16 * PP);
#pragma unroll 2
  for (int h = 0; h < NHEAD; ++h) {
    b16x8 aq = *(const b16x8*)(QHS + (w * 16 + l15) * SP + h * HDIM + lg * 8);
    f32x4 L[4];
#pragma unroll
    for (int nt = 0; nt < 4; ++nt) {
      b16x8 bk = *(const b16x8*)(KHS + (nt * 16 + l15) * SP + h * HDIM + lg * 8);
      L[nt] = MFMA(aq, bk, zero4);
    }
    // + rel-pos bias + window mask; pad rows/cols -> -1e9
#pragma unroll
    for (int nt = 0; nt < 4; ++nt) {
      const int cgl = nt * 16 + l15;
#pragma unroll
      for (int r = 0; r < 4; ++r) {
        const int rw = w * 16 + lg * 4 + r;
        if (rw < NTOK && cgl < NTOK) {
          const int ci = (rw / 7) * 13 + (rw % 7);
          const int jj = 48 - cgl;
          const int cj = (jj / 7) * 13 + (jj % 7);
          L[nt][r] += rpb[(ci + cj) * NHEAD + h] + maskw[rw * NTOK + cgl];
        } else {
          L[nt][r] = -1e9f;
        }
      }
    }
    // wave-parallel softmax: rows live across the 16-lane column group
#pragma unroll
    for (int r = 0; r < 4; ++r) {
      float m = fmaxf(fmaxf(L[0][r], L[1][r]), fmaxf(L[2][r], L[3][r]));
      m = fmaxf(m, __shfl_xor(m, 1));
      m = fmaxf(m, __shfl_xor(m, 2));
      m = fmaxf(m, __shfl_xor(m, 4));
      m = fmaxf(m, __shfl_xor(m, 8));
      float p0 = __expf(L[0][r] - m), p1 = __expf(L[1][r] - m);
      float p2 = __expf(L[2][r] - m), p3 = __expf(L[3][r] - m);
      float s = p0 + p1 + p2 + p3;
      s += __shfl_xor(s, 1);
      s += __shfl_xor(s, 2);
      s += __shfl_xor(s, 4);
      s += __shfl_xor(s, 8);
      const float is = 1.0f / s;
      L[0][r] = p0 * is; L[1][r] = p1 * is; L[2][r] = p2 * is; L[3][r] = p3 * is;
    }
    // P -> per-wave LDS (D-layout -> row-major), then PV
#pragma unroll
    for (int nt = 0; nt < 4; ++nt)
#pragma unroll
      for (int r = 0; r < 4; ++r)
        PB[(lg * 4 + r) * PP + nt * 16 + l15] = f2bf(L[nt][r]);
    f32x4 xa[2] = {zero4, zero4};
#pragma unroll
    for (int kk = 0; kk < 2; ++kk) {
      b16x8 ap = *(const b16x8*)(PB + l15 * PP + kk * 32 + lg * 8);
#pragma unroll
      for (int nv = 0; nv < 2; ++nv) {
        b16x8 bv = *(const b16x8*)(VHT + (h * HDIM + nv * 16 + l15) * VP + kk * 32 + lg * 8);
        xa[nv] = MFMA(ap, bv, xa[nv]);
      }
    }
    // x slice -> STG (reused as x buffer)
#pragma unroll
    for (int nv = 0; nv < 2; ++nv)
#pragma unroll
      for (int r = 0; r < 4; ++r)
        STG[(w * 16 + lg * 4 + r) * SP + h * HDIM + nv * 16 + l15] = f2bf(xa[nv][r]);
  }
  __syncthreads();

  // ---- output projection: wave w -> nt = w*3 + {0,1,2} ----
  {
    f32x4 acc[3][4];
#pragma unroll
    for (int j = 0; j < 3; ++j)
#pragma unroll
      for (int m = 0; m < 4; ++m) acc[j][m] = zero4;
    const int nt0 = w * 3;
#pragma unroll
    for (int kk = 0; kk < 6; ++kk) {
      b16x8 a[4];
#pragma unroll
      for (int m = 0; m < 4; ++m)
        a[m] = *(const b16x8*)(STG + (m * 16 + l15) * SP + kk * 32 + lg * 8);
#pragma unroll
      for (int j = 0; j < 3; ++j) {
        const int col = (nt0 + j) * 16 + l15;
        b16x8 bw = *(const b16x8*)(WoB + col * CDIM + kk * 32 + lg * 8);
#pragma unroll
        for (int m = 0; m < 4; ++m) acc[j][m] = MFMA(a[m], bw, acc[j][m]);
      }
    }
    float* dst = outg + (size_t)b * (NTOK * CDIM);
#pragma unroll
    for (int j = 0; j < 3; ++j) {
      const int col = (nt0 + j) * 16 + l15;
      const float bias = bo[col];
#pragma unroll
      for (int m = 0; m < 4; ++m)
#pragma unroll
        for (int r = 0; r < 4; ++r) {
          const int row = m * 16 + lg * 4 + r;
          if (row < NTOK) dst[row * CDIM + col] = acc[j][m][r] + bias;
        }
    }
  }
}

extern "C" void kernel_launch(void* const* d_in, const int* in_sizes, int n_in,
                              void* d_out, int out_size, void* d_ws, size_t ws_size,
                              hipStream_t stream) {
  const float* q = (const float*)d_in[0];
  const float* kv = (const float*)d_in[1];
  const float* mask = (const float*)d_in[2];
  const float* Wq = (const float*)d_in[3];
  const float* bq = (const float*)d_in[4];
  const float* Wkv = (const float*)d_in[5];
  const float* bkv = (const float*)d_in[6];
  const float* Wo = (const float*)d_in[7];
  const float* bo = (const float*)d_in[8];
  const float* rpb = (const float*)d_in[9];
  short* wsW = (short*)d_ws;

  const int B = in_sizes[0] / (NTOK * CDIM);
  const int nW = in_sizes[2] / (NTOK * NTOK);

  prep_kernel<<<288, 256, 0, stream>>>(Wq, Wkv, Wo, wsW);
  wmsa_kernel<<<B, 256, 0, stream>>>(q, kv, mask, bq, bkv, bo, rpb, wsW,
                                     (float*)d_out, nW);
}

// Round 3
// 1116.500 us; speedup vs baseline: 1.0233x; 1.0233x over previous
//
#include <hip/hip_runtime.h>

#define NTOK 49
#define CDIM 192
#define NHEAD 6
#define HDIM 32

typedef float f32x4 __attribute__((ext_vector_type(4), may_alias));
typedef short b16x8 __attribute__((ext_vector_type(8), may_alias));
typedef short b16x4 __attribute__((ext_vector_type(4), may_alias));

__device__ __forceinline__ f32x4 MFMA(b16x8 a, b16x8 b, f32x4 c) {
  return __builtin_amdgcn_mfma_f32_16x16x32_bf16(a, b, c, 0, 0, 0);
}

__device__ __forceinline__ short f2bf(float f) {
  unsigned u = __builtin_bit_cast(unsigned, f);
  u += 0x7FFFu + ((u >> 16) & 1u);  // round-to-nearest-even
  return (short)(u >> 16);
}

// XOR swizzle for [64][192] bf16 tiles: 8-short (16B) granules, bijective
// within each 8-row stripe; makes 16-row-column b128 reads 2-way (free).
__device__ __forceinline__ int swz(int row, int col) {
  return row * CDIM + (col ^ ((row & 7) << 3));
}

// ---- prep 1: fp32 weights -> bf16 ws. Wq pre-scaled by D^-0.5 ----
// ws shorts: [0,36864) Wq | [36864,110592) Wkv | [110592,147456) Wo
__global__ void prep_w(const float* __restrict__ Wq, const float* __restrict__ Wkv,
                       const float* __restrict__ Wo, short* __restrict__ wsW) {
  const float scale = 0.17677669529663687f;
  int i = blockIdx.x * 256 + threadIdx.x;
  if (i >= 147456) return;
  float v;
  if (i < 36864)        v = Wq[i] * scale;
  else if (i < 110592)  v = Wkv[i - 36864];
  else                  v = Wo[i - 110592];
  wsW[i] = f2bf(v);
}

// ---- prep 2: fused rel-pos-bias + mask table [nW][H][49][49] f32 ----
__global__ void prep_bm(const float* __restrict__ rpb, const float* __restrict__ maskg,
                        float* __restrict__ bmt, int nW) {
  int idx = blockIdx.x * 256 + threadIdx.x;
  int total = nW * NHEAD * NTOK * NTOK;
  if (idx >= total) return;
  int p = idx % (NTOK * NTOK);
  int h = (idx / (NTOK * NTOK)) % NHEAD;
  int wi = idx / (NHEAD * NTOK * NTOK);
  int i = p / NTOK, j = p % NTOK;
  int ci = (i / 7) * 13 + (i % 7);
  int jj = 48 - j;
  int cj = (jj / 7) * 13 + (jj % 7);
  bmt[idx] = rpb[(ci + cj) * NHEAD + h] + maskg[wi * (NTOK * NTOK) + p];
}

// Fused window-MSA: one window per block, 8 waves (512 threads), 73.5 KB LDS
// -> 2 blocks/CU, 16 waves/CU.
// LDS lifetimes: SH: kv-stage -> qh -> per-wave P region.
//                KH: kh -> x.   VT: vhT (whole kernel).
__global__ __launch_bounds__(512, 4) void wmsa_kernel(
    const float* __restrict__ qg, const float* __restrict__ kvg,
    const float* __restrict__ bq, const float* __restrict__ bkv,
    const float* __restrict__ bo, const short* __restrict__ wsW,
    const float* __restrict__ bmt, float* __restrict__ outg, int nW) {
  __shared__ short lds[37632];     // 75264 B
  short* SH = lds;                 // [64][192] swizzled
  short* KH = lds + 12288;         // [64][192] swizzled
  short* VT = lds + 24576;         // [192][68] vhT[c][token]

  const int b = blockIdx.x;
  const int tid = threadIdx.x;
  const int w = tid >> 6;          // wave 0..7
  const int lane = tid & 63;
  const int l15 = lane & 15;
  const int lg = lane >> 4;
  const float scale = 0.17677669529663687f;
  const f32x4 zero4 = {0.f, 0.f, 0.f, 0.f};

  const short* WqB = wsW;
  const short* WkvB = wsW + 36864;
  const short* WoB = wsW + 110592;

  const float* qsrc = qg + (size_t)b * (NTOK * CDIM);
  const float* kvsrc = kvg + (size_t)b * (NTOK * CDIM);

  // ---- issue q loads early (consumed after kv-proj; hides HBM latency) ----
  f32x4 qreg[6];
#pragma unroll
  for (int it = 0; it < 6; ++it) {
    int idx = tid + it * 512;
    int r = idx / 48, c4 = idx % 48;
    qreg[it] = (r < NTOK) ? *(const f32x4*)(qsrc + r * CDIM + c4 * 4) : zero4;
  }
  // ---- stage kv -> SH bf16 (rows 49..63 zero) ----
#pragma unroll
  for (int it = 0; it < 6; ++it) {
    int idx = tid + it * 512;
    int r = idx / 48, c4 = idx % 48;
    f32x4 v = (r < NTOK) ? *(const f32x4*)(kvsrc + r * CDIM + c4 * 4) : zero4;
    b16x4 o = {f2bf(v[0]), f2bf(v[1]), f2bf(v[2]), f2bf(v[3])};
    *(b16x4*)(SH + swz(r, c4 * 4)) = o;
  }
  __syncthreads();  // B1: kv staged

  // ---- kv projection: 24 col-tiles, wave w -> nt = w*3 + {0,1,2} ----
#pragma unroll
  for (int jj = 0; jj < 3; ++jj) {
    const int nt = w * 3 + jj;
    const int col = nt * 16 + l15;  // 0..383
    f32x4 acc[4];
#pragma unroll
    for (int m = 0; m < 4; ++m) acc[m] = zero4;
#pragma unroll
    for (int kk = 0; kk < 6; ++kk) {
      b16x8 bw = *(const b16x8*)(WkvB + col * CDIM + kk * 32 + lg * 8);
#pragma unroll
      for (int m = 0; m < 4; ++m) {
        b16x8 a = *(const b16x8*)(SH + swz(m * 16 + l15, kk * 32 + lg * 8));
        acc[m] = MFMA(a, bw, acc[m]);
      }
    }
    const float bias = bkv[col];
    if (col < CDIM) {  // K half -> KH[token][col]
#pragma unroll
      for (int m = 0; m < 4; ++m)
#pragma unroll
        for (int r = 0; r < 4; ++r)
          KH[swz(m * 16 + lg * 4 + r, col)] = f2bf(acc[m][r] + bias);
    } else {  // V half -> VT[c][token]
      const int c = col - CDIM;
#pragma unroll
      for (int m = 0; m < 4; ++m) {
        b16x4 o = {f2bf(acc[m][0] + bias), f2bf(acc[m][1] + bias),
                   f2bf(acc[m][2] + bias), f2bf(acc[m][3] + bias)};
        *(b16x4*)(VT + c * 68 + m * 16 + lg * 4) = o;
      }
    }
  }
  __syncthreads();  // B2: kv-proj done reading SH

  // ---- write q (from regs) -> SH ----
#pragma unroll
  for (int it = 0; it < 6; ++it) {
    int idx = tid + it * 512;
    int r = idx / 48, c4 = idx % 48;
    b16x4 o = {f2bf(qreg[it][0]), f2bf(qreg[it][1]), f2bf(qreg[it][2]), f2bf(qreg[it][3])};
    *(b16x4*)(SH + swz(r, c4 * 4)) = o;
  }
  __syncthreads();  // B3: q staged

  // ---- q projection: 48 (j,m) pairs / 8 waves; acc in regs, write after bar ----
  f32x4 qacc[6];
#pragma unroll
  for (int t = 0; t < 6; ++t) qacc[t] = zero4;
#pragma unroll
  for (int t = 0; t < 6; ++t) {
    const int pid = w * 6 + t;
    const int j = pid >> 2, m = pid & 3;
    const int col = j * 16 + l15;
#pragma unroll
    for (int kk = 0; kk < 6; ++kk) {
      b16x8 a = *(const b16x8*)(SH + swz(m * 16 + l15, kk * 32 + lg * 8));
      b16x8 bw = *(const b16x8*)(WqB + col * CDIM + kk * 32 + lg * 8);
      qacc[t] = MFMA(a, bw, qacc[t]);
    }
  }
  __syncthreads();  // B4: all q reads from SH done
#pragma unroll
  for (int t = 0; t < 6; ++t) {
    const int pid = w * 6 + t;
    const int j = pid >> 2, m = pid & 3;
    const int col = j * 16 + l15;
    const float bias = bq[col] * scale;
#pragma unroll
    for (int r = 0; r < 4; ++r)
      SH[swz(m * 16 + lg * 4 + r, col)] = f2bf(qacc[t][r] + bias);
  }
  __syncthreads();  // B5: qh ready

  // ---- attention: wave w -> rowblock R = w>>1, heads h0 = (w&1)*3 .. +2 ----
  // P region in SH: rows R*16..+15, cols (w&1)*96..+63 — disjoint from the
  // qh columns the partner wave reads, so no barrier inside the head loop.
  const int R = w >> 1, hw = w & 1, h0 = hw * 3;
  b16x8 aq[3];
#pragma unroll
  for (int hh = 0; hh < 3; ++hh)
    aq[hh] = *(const b16x8*)(SH + swz(R * 16 + l15, (h0 + hh) * 32 + lg * 8));
  const float* btb = bmt + (size_t)(b % nW) * (NHEAD * NTOK * NTOK);
  f32x4 xh[3][2];
#pragma unroll
  for (int hh = 0; hh < 3; ++hh) {
    xh[hh][0] = zero4;
    xh[hh][1] = zero4;
  }
#pragma unroll
  for (int hh = 0; hh < 3; ++hh) {
    const int h = h0 + hh;
    f32x4 L[4];
#pragma unroll
    for (int nt = 0; nt < 4; ++nt) {
      b16x8 bk = *(const b16x8*)(KH + swz(nt * 16 + l15, h * 32 + lg * 8));
      L[nt] = MFMA(aq[hh], bk, zero4);
    }
    const float* bt = btb + h * (NTOK * NTOK);
#pragma unroll
    for (int nt = 0; nt < 4; ++nt) {
      const int cgl = nt * 16 + l15;
#pragma unroll
      for (int r = 0; r < 4; ++r) {
        const int rw = R * 16 + lg * 4 + r;
        if (rw < NTOK && cgl < NTOK) L[nt][r] += bt[rw * NTOK + cgl];
        else                          L[nt][r] = -1e9f;
      }
    }
#pragma unroll
    for (int r = 0; r < 4; ++r) {
      float m = fmaxf(fmaxf(L[0][r], L[1][r]), fmaxf(L[2][r], L[3][r]));
      m = fmaxf(m, __shfl_xor(m, 1));
      m = fmaxf(m, __shfl_xor(m, 2));
      m = fmaxf(m, __shfl_xor(m, 4));
      m = fmaxf(m, __shfl_xor(m, 8));
      float p0 = __expf(L[0][r] - m), p1 = __expf(L[1][r] - m);
      float p2 = __expf(L[2][r] - m), p3 = __expf(L[3][r] - m);
      float s = p0 + p1 + p2 + p3;
      s += __shfl_xor(s, 1);
      s += __shfl_xor(s, 2);
      s += __shfl_xor(s, 4);
      s += __shfl_xor(s, 8);
      const float is = 1.0f / s;
      L[0][r] = p0 * is; L[1][r] = p1 * is; L[2][r] = p2 * is; L[3][r] = p3 * is;
    }
    // P -> SH (own region), then PV
#pragma unroll
    for (int nt = 0; nt < 4; ++nt)
#pragma unroll
      for (int r = 0; r < 4; ++r)
        SH[swz(R * 16 + lg * 4 + r, hw * 96 + nt * 16 + l15)] = f2bf(L[nt][r]);
#pragma unroll
    for (int kk = 0; kk < 2; ++kk) {
      b16x8 ap = *(const b16x8*)(SH + swz(R * 16 + l15, hw * 96 + kk * 32 + lg * 8));
#pragma unroll
      for (int nv = 0; nv < 2; ++nv) {
        b16x8 bv = *(const b16x8*)(VT + (h * 32 + nv * 16 + l15) * 68 + kk * 32 + lg * 8);
        xh[hh][nv] = MFMA(ap, bv, xh[hh][nv]);
      }
    }
  }
  __syncthreads();  // B6: all KH (kh) reads done
  // ---- x -> KH ----
#pragma unroll
  for (int hh = 0; hh < 3; ++hh)
#pragma unroll
    for (int nv = 0; nv < 2; ++nv)
#pragma unroll
      for (int r = 0; r < 4; ++r)
        KH[swz(R * 16 + lg * 4 + r, (h0 + hh) * 32 + nv * 16 + l15)] =
            f2bf(xh[hh][nv][r]);
  __syncthreads();  // B7: x ready

  // ---- output projection: 48 (j,m) pairs / 8 waves ----
  f32x4 oacc[6];
#pragma unroll
  for (int t = 0; t < 6; ++t) oacc[t] = zero4;
#pragma unroll
  for (int t = 0; t < 6; ++t) {
    const int pid = w * 6 + t;
    const int j = pid >> 2, m = pid & 3;
    const int col = j * 16 + l15;
#pragma unroll
    for (int kk = 0; kk < 6; ++kk) {
      b16x8 a = *(const b16x8*)(KH + swz(m * 16 + l15, kk * 32 + lg * 8));
      b16x8 bw = *(const b16x8*)(WoB + col * CDIM + kk * 32 + lg * 8);
      oacc[t] = MFMA(a, bw, oacc[t]);
    }
  }
  float* dst = outg + (size_t)b * (NTOK * CDIM);
#pragma unroll
  for (int t = 0; t < 6; ++t) {
    const int pid = w * 6 + t;
    const int j = pid >> 2, m = pid & 3;
    const int col = j * 16 + l15;
    const float bias = bo[col];
#pragma unroll
    for (int r = 0; r < 4; ++r) {
      const int row = m * 16 + lg * 4 + r;
      if (row < NTOK) dst[row * CDIM + col] = oacc[t][r] + bias;
    }
  }
}

extern "C" void kernel_launch(void* const* d_in, const int* in_sizes, int n_in,
                              void* d_out, int out_size, void* d_ws, size_t ws_size,
                              hipStream_t stream) {
  const float* q = (const float*)d_in[0];
  const float* kv = (const float*)d_in[1];
  const float* mask = (const float*)d_in[2];
  const float* Wq = (const float*)d_in[3];
  const float* bq = (const float*)d_in[4];
  const float* Wkv = (const float*)d_in[5];
  const float* bkv = (const float*)d_in[6];
  const float* Wo = (const float*)d_in[7];
  const float* bo = (const float*)d_in[8];
  const float* rpb = (const float*)d_in[9];
  short* wsW = (short*)d_ws;
  float* bmt = (float*)((char*)d_ws + 294912);  // after weights

  const int B = in_sizes[0] / (NTOK * CDIM);
  const int nW = in_sizes[2] / (NTOK * NTOK);

  prep_w<<<576, 256, 0, stream>>>(Wq, Wkv, Wo, wsW);
  {
    int total = nW * NHEAD * NTOK * NTOK;
    prep_bm<<<(total + 255) / 256, 256, 0, stream>>>(rpb, mask, bmt, nW);
  }
  wmsa_kernel<<<B, 512, 0, stream>>>(q, kv, bq, bkv, bo, wsW, bmt,
                                     (float*)d_out, nW);
}

// Round 4
// 1019.207 us; speedup vs baseline: 1.1210x; 1.0955x over previous
//
#include <hip/hip_runtime.h>

#define NTOK 49
#define CDIM 192
#define NHEAD 6
#define HDIM 32

typedef float f32x4 __attribute__((ext_vector_type(4), may_alias));
typedef short b16x8 __attribute__((ext_vector_type(8), may_alias));
typedef short b16x4 __attribute__((ext_vector_type(4), may_alias));

__device__ __forceinline__ f32x4 MFMA(b16x8 a, b16x8 b, f32x4 c) {
  return __builtin_amdgcn_mfma_f32_16x16x32_bf16(a, b, c, 0, 0, 0);
}

__device__ __forceinline__ short f2bf(float f) {
  unsigned u = __builtin_bit_cast(unsigned, f);
  u += 0x7FFFu + ((u >> 16) & 1u);  // round-to-nearest-even
  return (short)(u >> 16);
}

// XOR swizzle for [64][192] bf16 tiles: 8-short (16B) granules, bijective
// within each 8-row stripe; makes 16-row-column b128 reads 2-way (free).
__device__ __forceinline__ int swz(int row, int col) {
  return row * CDIM + (col ^ ((row & 7) << 3));
}

// ---- prep 1: fp32 weights -> bf16 ws. Wq pre-scaled by D^-0.5 ----
// ws shorts: [0,36864) Wq | [36864,110592) Wkv | [110592,147456) Wo
__global__ void prep_w(const float* __restrict__ Wq, const float* __restrict__ Wkv,
                       const float* __restrict__ Wo, short* __restrict__ wsW) {
  const float scale = 0.17677669529663687f;
  int i = blockIdx.x * 256 + threadIdx.x;
  if (i >= 147456) return;
  float v;
  if (i < 36864)        v = Wq[i] * scale;
  else if (i < 110592)  v = Wkv[i - 36864];
  else                  v = Wo[i - 110592];
  wsW[i] = f2bf(v);
}

// ---- prep 2: rel-pos-bias table [H][49][49] f32 (57.6 KB, stays L2-hot) ----
__global__ void prep_bias(const float* __restrict__ rpb, float* __restrict__ bias_t) {
  int idx = blockIdx.x * 256 + threadIdx.x;
  if (idx >= NHEAD * NTOK * NTOK) return;
  int h = idx / (NTOK * NTOK);
  int p = idx % (NTOK * NTOK);
  int i = p / NTOK, j = p % NTOK;
  int ci = (i / 7) * 13 + (i % 7);
  int jj = 48 - j;
  int cj = (jj / 7) * 13 + (jj % 7);
  bias_t[idx] = rpb[(ci + cj) * NHEAD + h];
}

// Fused window-MSA: one window per block, 8 waves (512 threads), 73.5 KB LDS
// -> 2 blocks/CU, 16 waves/CU.
// LDS layout (shorts): SH [0,12288) | VT [12288,25344) | KH [25344,37632).
// SH: kv-stage -> qh -> per-wave P.  VT: vhT.  KH: kh -> x.
// Epilogue: SH+VT (contiguous, both dead) reused as f32 [49][204] bounce so
// the final stores are fully coalesced f32x4 (full-line HBM writes).
__global__ __launch_bounds__(512, 4) void wmsa_kernel(
    const float* __restrict__ qg, const float* __restrict__ kvg,
    const float* __restrict__ maskg, const float* __restrict__ bq,
    const float* __restrict__ bkv, const float* __restrict__ bo,
    const short* __restrict__ wsW, const float* __restrict__ bias_t,
    float* __restrict__ outg, int nW) {
  __shared__ short lds[37632];     // 75264 B
  short* SH = lds;                 // [64][192] swizzled
  short* VT = lds + 12288;         // [192][68] vhT[c][token]
  short* KH = lds + 25344;         // [64][192] swizzled
  float* BF = (float*)lds;         // epilogue bounce [49][204] f32 (40 KB)

  const int b = blockIdx.x;
  const int tid = threadIdx.x;
  const int w = tid >> 6;          // wave 0..7
  const int lane = tid & 63;
  const int l15 = lane & 15;
  const int lg = lane >> 4;
  const float scale = 0.17677669529663687f;
  const f32x4 zero4 = {0.f, 0.f, 0.f, 0.f};

  const short* WqB = wsW;
  const short* WkvB = wsW + 36864;
  const short* WoB = wsW + 110592;

  const float* qsrc = qg + (size_t)b * (NTOK * CDIM);
  const float* kvsrc = kvg + (size_t)b * (NTOK * CDIM);

  // ---- issue q loads early (consumed after kv-proj; hides HBM latency) ----
  f32x4 qreg[6];
#pragma unroll
  for (int it = 0; it < 6; ++it) {
    int idx = tid + it * 512;
    int r = idx / 48, c4 = idx % 48;
    qreg[it] = (r < NTOK) ? *(const f32x4*)(qsrc + r * CDIM + c4 * 4) : zero4;
  }
  // ---- stage kv -> SH bf16 (rows 49..63 zero) ----
#pragma unroll
  for (int it = 0; it < 6; ++it) {
    int idx = tid + it * 512;
    int r = idx / 48, c4 = idx % 48;
    f32x4 v = (r < NTOK) ? *(const f32x4*)(kvsrc + r * CDIM + c4 * 4) : zero4;
    b16x4 o = {f2bf(v[0]), f2bf(v[1]), f2bf(v[2]), f2bf(v[3])};
    *(b16x4*)(SH + swz(r, c4 * 4)) = o;
  }
  __syncthreads();  // B1: kv staged

  // ---- kv projection: 24 col-tiles, wave w -> nt = w*3 + {0,1,2} ----
  // reads SH, writes KH/VT (disjoint) -> no reg hold needed
#pragma unroll
  for (int jj = 0; jj < 3; ++jj) {
    const int nt = w * 3 + jj;
    const int col = nt * 16 + l15;  // 0..383
    f32x4 acc[4];
#pragma unroll
    for (int m = 0; m < 4; ++m) acc[m] = zero4;
#pragma unroll
    for (int kk = 0; kk < 6; ++kk) {
      b16x8 bw = *(const b16x8*)(WkvB + col * CDIM + kk * 32 + lg * 8);
#pragma unroll
      for (int m = 0; m < 4; ++m) {
        b16x8 a = *(const b16x8*)(SH + swz(m * 16 + l15, kk * 32 + lg * 8));
        acc[m] = MFMA(a, bw, acc[m]);
      }
    }
    const float bias = bkv[col];
    if (col < CDIM) {  // K half -> KH[token][col]
#pragma unroll
      for (int m = 0; m < 4; ++m)
#pragma unroll
        for (int r = 0; r < 4; ++r)
          KH[swz(m * 16 + lg * 4 + r, col)] = f2bf(acc[m][r] + bias);
    } else {  // V half -> VT[c][token]
      const int c = col - CDIM;
#pragma unroll
      for (int m = 0; m < 4; ++m) {
        b16x4 o = {f2bf(acc[m][0] + bias), f2bf(acc[m][1] + bias),
                   f2bf(acc[m][2] + bias), f2bf(acc[m][3] + bias)};
        *(b16x4*)(VT + c * 68 + m * 16 + lg * 4) = o;
      }
    }
  }
  __syncthreads();  // B2: kv-proj done reading SH

  // ---- write q (from regs) -> SH ----
#pragma unroll
  for (int it = 0; it < 6; ++it) {
    int idx = tid + it * 512;
    int r = idx / 48, c4 = idx % 48;
    b16x4 o = {f2bf(qreg[it][0]), f2bf(qreg[it][1]), f2bf(qreg[it][2]), f2bf(qreg[it][3])};
    *(b16x4*)(SH + swz(r, c4 * 4)) = o;
  }
  __syncthreads();  // B3: q staged

  // ---- q projection: 48 (j,m) pairs / 8 waves; acc in regs, write after bar ----
  f32x4 qacc[6];
#pragma unroll
  for (int t = 0; t < 6; ++t) qacc[t] = zero4;
#pragma unroll
  for (int t = 0; t < 6; ++t) {
    const int pid = w * 6 + t;
    const int j = pid >> 2, m = pid & 3;
    const int col = j * 16 + l15;
#pragma unroll
    for (int kk = 0; kk < 6; ++kk) {
      b16x8 a = *(const b16x8*)(SH + swz(m * 16 + l15, kk * 32 + lg * 8));
      b16x8 bw = *(const b16x8*)(WqB + col * CDIM + kk * 32 + lg * 8);
      qacc[t] = MFMA(a, bw, qacc[t]);
    }
  }
  __syncthreads();  // B4: all q reads from SH done
#pragma unroll
  for (int t = 0; t < 6; ++t) {
    const int pid = w * 6 + t;
    const int j = pid >> 2, m = pid & 3;
    const int col = j * 16 + l15;
    const float bias = bq[col] * scale;
#pragma unroll
    for (int r = 0; r < 4; ++r)
      SH[swz(m * 16 + lg * 4 + r, col)] = f2bf(qacc[t][r] + bias);
  }
  __syncthreads();  // B5: qh ready

  // ---- attention: wave w -> rowblock R = w>>1, heads h0 = (w&1)*3 .. +2 ----
  const int R = w >> 1, hw = w & 1, h0 = hw * 3;
  b16x8 aq[3];
#pragma unroll
  for (int hh = 0; hh < 3; ++hh)
    aq[hh] = *(const b16x8*)(SH + swz(R * 16 + l15, (h0 + hh) * 32 + lg * 8));

  // mask hoist: load once, reuse across the 3 heads (guarded: stay in-bounds)
  const float* maskw = maskg + (size_t)(b % nW) * (NTOK * NTOK);
  float maskv[4][4];
#pragma unroll
  for (int nt = 0; nt < 4; ++nt) {
    const int cgl = nt * 16 + l15;
#pragma unroll
    for (int r = 0; r < 4; ++r) {
      const int rw = R * 16 + lg * 4 + r;
      maskv[nt][r] = (rw < NTOK && cgl < NTOK) ? maskw[rw * NTOK + cgl] : 0.f;
    }
  }

  f32x4 xh[3][2];
#pragma unroll
  for (int hh = 0; hh < 3; ++hh) {
    xh[hh][0] = zero4;
    xh[hh][1] = zero4;
  }
#pragma unroll
  for (int hh = 0; hh < 3; ++hh) {
    const int h = h0 + hh;
    f32x4 L[4];
#pragma unroll
    for (int nt = 0; nt < 4; ++nt) {
      b16x8 bk = *(const b16x8*)(KH + swz(nt * 16 + l15, h * 32 + lg * 8));
      L[nt] = MFMA(aq[hh], bk, zero4);
    }
    const float* bt = bias_t + h * (NTOK * NTOK);
#pragma unroll
    for (int nt = 0; nt < 4; ++nt) {
      const int cgl = nt * 16 + l15;
#pragma unroll
      for (int r = 0; r < 4; ++r) {
        const int rw = R * 16 + lg * 4 + r;
        if (rw < NTOK && cgl < NTOK) L[nt][r] += bt[rw * NTOK + cgl] + maskv[nt][r];
        else                          L[nt][r] = -1e9f;
      }
    }
#pragma unroll
    for (int r = 0; r < 4; ++r) {
      float m = fmaxf(fmaxf(L[0][r], L[1][r]), fmaxf(L[2][r], L[3][r]));
      m = fmaxf(m, __shfl_xor(m, 1));
      m = fmaxf(m, __shfl_xor(m, 2));
      m = fmaxf(m, __shfl_xor(m, 4));
      m = fmaxf(m, __shfl_xor(m, 8));
      float p0 = __expf(L[0][r] - m), p1 = __expf(L[1][r] - m);
      float p2 = __expf(L[2][r] - m), p3 = __expf(L[3][r] - m);
      float s = p0 + p1 + p2 + p3;
      s += __shfl_xor(s, 1);
      s += __shfl_xor(s, 2);
      s += __shfl_xor(s, 4);
      s += __shfl_xor(s, 8);
      const float is = 1.0f / s;
      L[0][r] = p0 * is; L[1][r] = p1 * is; L[2][r] = p2 * is; L[3][r] = p3 * is;
    }
    // P -> SH (own region: rows R*16..+15, cols hw*96..+63), then PV
#pragma unroll
    for (int nt = 0; nt < 4; ++nt)
#pragma unroll
      for (int r = 0; r < 4; ++r)
        SH[swz(R * 16 + lg * 4 + r, hw * 96 + nt * 16 + l15)] = f2bf(L[nt][r]);
#pragma unroll
    for (int kk = 0; kk < 2; ++kk) {
      b16x8 ap = *(const b16x8*)(SH + swz(R * 16 + l15, hw * 96 + kk * 32 + lg * 8));
#pragma unroll
      for (int nv = 0; nv < 2; ++nv) {
        b16x8 bv = *(const b16x8*)(VT + (h * 32 + nv * 16 + l15) * 68 + kk * 32 + lg * 8);
        xh[hh][nv] = MFMA(ap, bv, xh[hh][nv]);
      }
    }
  }
  __syncthreads();  // B6: all KH (kh) reads done
  // ---- x -> KH ----
#pragma unroll
  for (int hh = 0; hh < 3; ++hh)
#pragma unroll
    for (int nv = 0; nv < 2; ++nv)
#pragma unroll
      for (int r = 0; r < 4; ++r)
        KH[swz(R * 16 + lg * 4 + r, (h0 + hh) * 32 + nv * 16 + l15)] =
            f2bf(xh[hh][nv][r]);
  __syncthreads();  // B7: x ready (SH, VT now dead -> bounce region)

  // ---- output projection -> f32 bounce (BF stride 204: 2-way banks, 16B-aligned rows) ----
#pragma unroll
  for (int t = 0; t < 6; ++t) {
    const int pid = w * 6 + t;
    const int j = pid >> 2, m = pid & 3;
    const int col = j * 16 + l15;
    f32x4 oacc = zero4;
#pragma unroll
    for (int kk = 0; kk < 6; ++kk) {
      b16x8 a = *(const b16x8*)(KH + swz(m * 16 + l15, kk * 32 + lg * 8));
      b16x8 bw = *(const b16x8*)(WoB + col * CDIM + kk * 32 + lg * 8);
      oacc = MFMA(a, bw, oacc);
    }
    const float bias = bo[col];
#pragma unroll
    for (int r = 0; r < 4; ++r) {
      const int row = m * 16 + lg * 4 + r;
      if (row < NTOK) BF[row * 204 + col] = oacc[r] + bias;
    }
  }
  __syncthreads();  // B8: bounce ready

  // ---- fully coalesced output stores (1 KB contiguous per wave-instr) ----
  float* dst = outg + (size_t)b * (NTOK * CDIM);
#pragma unroll
  for (int t = 0; t < 5; ++t) {
    int idx = tid + t * 512;
    if (idx < NTOK * 48) {
      int row = idx / 48, c4 = idx % 48;
      f32x4 v = *(const f32x4*)(BF + row * 204 + c4 * 4);
      *(f32x4*)(dst + row * CDIM + c4 * 4) = v;
    }
  }
}

extern "C" void kernel_launch(void* const* d_in, const int* in_sizes, int n_in,
                              void* d_out, int out_size, void* d_ws, size_t ws_size,
                              hipStream_t stream) {
  const float* q = (const float*)d_in[0];
  const float* kv = (const float*)d_in[1];
  const float* mask = (const float*)d_in[2];
  const float* Wq = (const float*)d_in[3];
  const float* bq = (const float*)d_in[4];
  const float* Wkv = (const float*)d_in[5];
  const float* bkv = (const float*)d_in[6];
  const float* Wo = (const float*)d_in[7];
  const float* bo = (const float*)d_in[8];
  const float* rpb = (const float*)d_in[9];
  short* wsW = (short*)d_ws;
  float* bias_t = (float*)((char*)d_ws + 294912);  // [6][49][49] f32, 57.6 KB

  const int B = in_sizes[0] / (NTOK * CDIM);
  const int nW = in_sizes[2] / (NTOK * NTOK);

  prep_w<<<576, 256, 0, stream>>>(Wq, Wkv, Wo, wsW);
  prep_bias<<<57, 256, 0, stream>>>(rpb, bias_t);
  wmsa_kernel<<<B, 512, 0, stream>>>(q, kv, mask, bq, bkv, bo, wsW, bias_t,
                                     (float*)d_out, nW);
}

// Round 5
// 894.352 us; speedup vs baseline: 1.2775x; 1.1396x over previous
//
#include <hip/hip_runtime.h>

#define NTOK 49
#define CDIM 192
#define NHEAD 6
#define HDIM 32

typedef float f32x4 __attribute__((ext_vector_type(4), may_alias));
typedef short b16x8 __attribute__((ext_vector_type(8), may_alias));
typedef short b16x4 __attribute__((ext_vector_type(4), may_alias));

__device__ __forceinline__ f32x4 MFMA(b16x8 a, b16x8 b, f32x4 c) {
  return __builtin_amdgcn_mfma_f32_16x16x32_bf16(a, b, c, 0, 0, 0);
}

__device__ __forceinline__ short f2bf(float f) {
  unsigned u = __builtin_bit_cast(unsigned, f);
  u += 0x7FFFu + ((u >> 16) & 1u);  // round-to-nearest-even
  return (short)(u >> 16);
}

// XOR swizzle for [64][192] bf16 tiles: 8-short (16B) granules, bijective
// within each 8-row stripe; makes 16-row-column b128 reads 2-way (free).
__device__ __forceinline__ int swz(int row, int col) {
  return row * CDIM + (col ^ ((row & 7) << 3));
}

// ---- prep 1: fp32 weights -> bf16 ws. Wq pre-scaled by D^-0.5 ----
// ws shorts: [0,36864) Wq | [36864,110592) Wkv | [110592,147456) Wo
__global__ void prep_w(const float* __restrict__ Wq, const float* __restrict__ Wkv,
                       const float* __restrict__ Wo, short* __restrict__ wsW) {
  const float scale = 0.17677669529663687f;
  int i = blockIdx.x * 256 + threadIdx.x;
  if (i >= 147456) return;
  float v;
  if (i < 36864)        v = Wq[i] * scale;
  else if (i < 110592)  v = Wkv[i - 36864];
  else                  v = Wo[i - 110592];
  wsW[i] = f2bf(v);
}

// ---- prep 2: rel-pos-bias table [H][49][49] f32 (57.6 KB, stays L2-hot) ----
__global__ void prep_bias(const float* __restrict__ rpb, float* __restrict__ bias_t) {
  int idx = blockIdx.x * 256 + threadIdx.x;
  if (idx >= NHEAD * NTOK * NTOK) return;
  int h = idx / (NTOK * NTOK);
  int p = idx % (NTOK * NTOK);
  int i = p / NTOK, j = p % NTOK;
  int ci = (i / 7) * 13 + (i % 7);
  int jj = 48 - j;
  int cj = (jj / 7) * 13 + (jj % 7);
  bias_t[idx] = rpb[(ci + cj) * NHEAD + h];
}

// Fused window-MSA: one window per block, 8 waves (512 threads), 73.5 KB LDS
// -> 2 blocks/CU. waves_per_eu(4) -> VGPR cap 128 (avoid the 64-reg spill trap).
// Phase order: stage q -> q-proj (per-wave own tile, qh never crosses waves)
// -> stage kv (regs held only during q-proj) -> kv-proj -> attention -> o-proj.
// LDS (shorts): SH [0,12288) | VT [12288,25344) | KH [25344,37632).
// SH: q-stage -> per-wave qh -> kv-stage -> per-wave P -> (w/ VT) f32 bounce.
// KH: kh -> x.  VT: vhT.
__global__ __attribute__((amdgpu_flat_work_group_size(512, 512),
                          amdgpu_waves_per_eu(4))) void wmsa_kernel(
    const float* __restrict__ qg, const float* __restrict__ kvg,
    const float* __restrict__ maskg, const float* __restrict__ bq,
    const float* __restrict__ bkv, const float* __restrict__ bo,
    const short* __restrict__ wsW, const float* __restrict__ bias_t,
    float* __restrict__ outg, int nW) {
  __shared__ short lds[37632];     // 75264 B
  short* SH = lds;                 // [64][192] swizzled
  short* VT = lds + 12288;         // [192][68] vhT[c][token]
  short* KH = lds + 25344;         // [64][192] swizzled
  float* BF = (float*)lds;         // epilogue bounce [49][204] f32 (40 KB)

  const int b = blockIdx.x;
  const int tid = threadIdx.x;
  const int w = tid >> 6;          // wave 0..7
  const int lane = tid & 63;
  const int l15 = lane & 15;
  const int lg = lane >> 4;
  const int R = w >> 1, hw = w & 1, h0 = hw * 3;
  const float scale = 0.17677669529663687f;
  const f32x4 zero4 = {0.f, 0.f, 0.f, 0.f};

  const short* WqB = wsW;
  const short* WkvB = wsW + 36864;
  const short* WoB = wsW + 110592;

  const float* qsrc = qg + (size_t)b * (NTOK * CDIM);
  const float* kvsrc = kvg + (size_t)b * (NTOK * CDIM);

  // ---- issue q and kv loads up front (HBM latency hidden under staging+q-proj) ----
  f32x4 qv[6], kvreg[6];
#pragma unroll
  for (int it = 0; it < 6; ++it) {
    int idx = tid + it * 512;
    int r = idx / 48, c4 = idx % 48;
    qv[it] = (r < NTOK) ? *(const f32x4*)(qsrc + r * CDIM + c4 * 4) : zero4;
  }
#pragma unroll
  for (int it = 0; it < 6; ++it) {
    int idx = tid + it * 512;
    int r = idx / 48, c4 = idx % 48;
    kvreg[it] = (r < NTOK) ? *(const f32x4*)(kvsrc + r * CDIM + c4 * 4) : zero4;
  }
  // ---- stage q -> SH bf16 (rows 49..63 zero) ----
#pragma unroll
  for (int it = 0; it < 6; ++it) {
    int idx = tid + it * 512;
    int r = idx / 48, c4 = idx % 48;
    b16x4 o = {f2bf(qv[it][0]), f2bf(qv[it][1]), f2bf(qv[it][2]), f2bf(qv[it][3])};
    *(b16x4*)(SH + swz(r, c4 * 4)) = o;
  }
  __syncthreads();  // B1: q staged

  // ---- q projection: wave computes exactly its own attention q-tile ----
  // rows m=R (16 rows), col-tiles j = hw*6 + t (96 cols = heads h0..h0+2)
  f32x4 qacc[6];
#pragma unroll
  for (int t = 0; t < 6; ++t) qacc[t] = zero4;
  {
    b16x8 aq6[6];
#pragma unroll
    for (int kk = 0; kk < 6; ++kk)
      aq6[kk] = *(const b16x8*)(SH + swz(R * 16 + l15, kk * 32 + lg * 8));
#pragma unroll
    for (int t = 0; t < 6; ++t) {
      const int col = (hw * 6 + t) * 16 + l15;
#pragma unroll
      for (int kk = 0; kk < 6; ++kk) {
        b16x8 bw = *(const b16x8*)(WqB + col * CDIM + kk * 32 + lg * 8);
        qacc[t] = MFMA(aq6[kk], bw, qacc[t]);
      }
    }
  }
  __syncthreads();  // B2: all q reads from SH done

  // ---- qh -> own SH region (rows R*16..+15, cols hw*96..+95), read aq ----
#pragma unroll
  for (int t = 0; t < 6; ++t) {
    const int col = (hw * 6 + t) * 16 + l15;
    const float bias = bq[col] * scale;
#pragma unroll
    for (int r = 0; r < 4; ++r)
      SH[swz(R * 16 + lg * 4 + r, hw * 96 + t * 16 + l15)] = f2bf(qacc[t][r] + bias);
  }
  b16x8 aq[3];
#pragma unroll
  for (int hh = 0; hh < 3; ++hh)
    aq[hh] = *(const b16x8*)(SH + swz(R * 16 + l15, hw * 96 + hh * 32 + lg * 8));
  __syncthreads();  // B3: qh reads done everywhere

  // ---- stage kv (from regs) -> SH ----
#pragma unroll
  for (int it = 0; it < 6; ++it) {
    int idx = tid + it * 512;
    int r = idx / 48, c4 = idx % 48;
    b16x4 o = {f2bf(kvreg[it][0]), f2bf(kvreg[it][1]), f2bf(kvreg[it][2]),
               f2bf(kvreg[it][3])};
    *(b16x4*)(SH + swz(r, c4 * 4)) = o;
  }
  __syncthreads();  // B4: kv staged

  // ---- kv projection: 24 col-tiles, wave w -> nt = w*3 + {0,1,2} ----
#pragma unroll
  for (int jj = 0; jj < 3; ++jj) {
    const int nt = w * 3 + jj;
    const int col = nt * 16 + l15;  // 0..383
    f32x4 acc[4];
#pragma unroll
    for (int m = 0; m < 4; ++m) acc[m] = zero4;
#pragma unroll
    for (int kk = 0; kk < 6; ++kk) {
      b16x8 bw = *(const b16x8*)(WkvB + col * CDIM + kk * 32 + lg * 8);
#pragma unroll
      for (int m = 0; m < 4; ++m) {
        b16x8 a = *(const b16x8*)(SH + swz(m * 16 + l15, kk * 32 + lg * 8));
        acc[m] = MFMA(a, bw, acc[m]);
      }
    }
    const float bias = bkv[col];
    if (col < CDIM) {  // K half -> KH[token][col]
#pragma unroll
      for (int m = 0; m < 4; ++m)
#pragma unroll
        for (int r = 0; r < 4; ++r)
          KH[swz(m * 16 + lg * 4 + r, col)] = f2bf(acc[m][r] + bias);
    } else {  // V half -> VT[c][token]
      const int c = col - CDIM;
#pragma unroll
      for (int m = 0; m < 4; ++m) {
        b16x4 o = {f2bf(acc[m][0] + bias), f2bf(acc[m][1] + bias),
                   f2bf(acc[m][2] + bias), f2bf(acc[m][3] + bias)};
        *(b16x4*)(VT + c * 68 + m * 16 + lg * 4) = o;
      }
    }
  }
  __syncthreads();  // B5: kh/vT ready; SH kv dead

  // ---- attention: wave w -> rows R*16..+15, heads h0..h0+2 ----
  const float* maskw = maskg + (size_t)(b % nW) * (NTOK * NTOK);
  float maskv[4][4];
#pragma unroll
  for (int nt = 0; nt < 4; ++nt) {
    const int cgl = nt * 16 + l15;
#pragma unroll
    for (int r = 0; r < 4; ++r) {
      const int rw = R * 16 + lg * 4 + r;
      maskv[nt][r] = (rw < NTOK && cgl < NTOK) ? maskw[rw * NTOK + cgl] : 0.f;
    }
  }

  f32x4 xh[3][2];
#pragma unroll
  for (int hh = 0; hh < 3; ++hh) {
    xh[hh][0] = zero4;
    xh[hh][1] = zero4;
  }
#pragma unroll
  for (int hh = 0; hh < 3; ++hh) {
    const int h = h0 + hh;
    f32x4 L[4];
#pragma unroll
    for (int nt = 0; nt < 4; ++nt) {
      b16x8 bk = *(const b16x8*)(KH + swz(nt * 16 + l15, h * 32 + lg * 8));
      L[nt] = MFMA(aq[hh], bk, zero4);
    }
    const float* bt = bias_t + h * (NTOK * NTOK);
#pragma unroll
    for (int nt = 0; nt < 4; ++nt) {
      const int cgl = nt * 16 + l15;
#pragma unroll
      for (int r = 0; r < 4; ++r) {
        const int rw = R * 16 + lg * 4 + r;
        if (rw < NTOK && cgl < NTOK) L[nt][r] += bt[rw * NTOK + cgl] + maskv[nt][r];
        else                          L[nt][r] = -1e9f;
      }
    }
#pragma unroll
    for (int r = 0; r < 4; ++r) {
      float m = fmaxf(fmaxf(L[0][r], L[1][r]), fmaxf(L[2][r], L[3][r]));
      m = fmaxf(m, __shfl_xor(m, 1));
      m = fmaxf(m, __shfl_xor(m, 2));
      m = fmaxf(m, __shfl_xor(m, 4));
      m = fmaxf(m, __shfl_xor(m, 8));
      float p0 = __expf(L[0][r] - m), p1 = __expf(L[1][r] - m);
      float p2 = __expf(L[2][r] - m), p3 = __expf(L[3][r] - m);
      float s = p0 + p1 + p2 + p3;
      s += __shfl_xor(s, 1);
      s += __shfl_xor(s, 2);
      s += __shfl_xor(s, 4);
      s += __shfl_xor(s, 8);
      const float is = 1.0f / s;
      L[0][r] = p0 * is; L[1][r] = p1 * is; L[2][r] = p2 * is; L[3][r] = p3 * is;
    }
    // P -> SH own region (rows R*16..+15, cols hw*96..+63), then PV
#pragma unroll
    for (int nt = 0; nt < 4; ++nt)
#pragma unroll
      for (int r = 0; r < 4; ++r)
        SH[swz(R * 16 + lg * 4 + r, hw * 96 + nt * 16 + l15)] = f2bf(L[nt][r]);
#pragma unroll
    for (int kk = 0; kk < 2; ++kk) {
      b16x8 ap = *(const b16x8*)(SH + swz(R * 16 + l15, hw * 96 + kk * 32 + lg * 8));
#pragma unroll
      for (int nv = 0; nv < 2; ++nv) {
        b16x8 bv = *(const b16x8*)(VT + (h * 32 + nv * 16 + l15) * 68 + kk * 32 + lg * 8);
        xh[hh][nv] = MFMA(ap, bv, xh[hh][nv]);
      }
    }
  }
  __syncthreads();  // B6: all KH (kh) reads done
  // ---- x -> KH ----
#pragma unroll
  for (int hh = 0; hh < 3; ++hh)
#pragma unroll
    for (int nv = 0; nv < 2; ++nv)
#pragma unroll
      for (int r = 0; r < 4; ++r)
        KH[swz(R * 16 + lg * 4 + r, (h0 + hh) * 32 + nv * 16 + l15)] =
            f2bf(xh[hh][nv][r]);
  __syncthreads();  // B7: x ready (SH, VT dead -> bounce region)

  // ---- output projection -> f32 bounce (stride 204) ----
#pragma unroll
  for (int t = 0; t < 6; ++t) {
    const int pid = w * 6 + t;
    const int j = pid >> 2, m = pid & 3;
    const int col = j * 16 + l15;
    f32x4 oacc = zero4;
#pragma unroll
    for (int kk = 0; kk < 6; ++kk) {
      b16x8 a = *(const b16x8*)(KH + swz(m * 16 + l15, kk * 32 + lg * 8));
      b16x8 bw = *(const b16x8*)(WoB + col * CDIM + kk * 32 + lg * 8);
      oacc = MFMA(a, bw, oacc);
    }
    const float bias = bo[col];
#pragma unroll
    for (int r = 0; r < 4; ++r) {
      const int row = m * 16 + lg * 4 + r;
      if (row < NTOK) BF[row * 204 + col] = oacc[r] + bias;
    }
  }
  __syncthreads();  // B8: bounce ready

  // ---- fully coalesced output stores (16B/lane contiguous) ----
  float* dst = outg + (size_t)b * (NTOK * CDIM);
#pragma unroll
  for (int t = 0; t < 5; ++t) {
    int idx = tid + t * 512;
    if (idx < NTOK * 48) {
      int row = idx / 48, c4 = idx % 48;
      f32x4 v = *(const f32x4*)(BF + row * 204 + c4 * 4);
      *(f32x4*)(dst + row * CDIM + c4 * 4) = v;
    }
  }
}

extern "C" void kernel_launch(void* const* d_in, const int* in_sizes, int n_in,
                              void* d_out, int out_size, void* d_ws, size_t ws_size,
                              hipStream_t stream) {
  const float* q = (const float*)d_in[0];
  const float* kv = (const float*)d_in[1];
  const float* mask = (const float*)d_in[2];
  const float* Wq = (const float*)d_in[3];
  const float* bq = (const float*)d_in[4];
  const float* Wkv = (const float*)d_in[5];
  const float* bkv = (const float*)d_in[6];
  const float* Wo = (const float*)d_in[7];
  const float* bo = (const float*)d_in[8];
  const float* rpb = (const float*)d_in[9];
  short* wsW = (short*)d_ws;
  float* bias_t = (float*)((char*)d_ws + 294912);  // [6][49][49] f32, 57.6 KB

  const int B = in_sizes[0] / (NTOK * CDIM);
  const int nW = in_sizes[2] / (NTOK * NTOK);

  prep_w<<<576, 256, 0, stream>>>(Wq, Wkv, Wo, wsW);
  prep_bias<<<57, 256, 0, stream>>>(rpb, bias_t);
  wmsa_kernel<<<B, 512, 0, stream>>>(q, kv, mask, bq, bkv, bo, wsW, bias_t,
                                     (float*)d_out, nW);
}